// Round 11
// baseline (1005.841 us; speedup 1.0000x reference)
//
#include <hip/hip_runtime.h>

typedef short short8 __attribute__((ext_vector_type(8)));
typedef float f32x4 __attribute__((ext_vector_type(4)));
typedef unsigned short u16;

#define NTOK 16281
#define NPAD 16384
#define NPATH 281
#define HEADS 8
#define QT_PATH 18          // ceil(281/16)
#define CHUNK 2036          // ceil(16281/8) key-split for path queries
#define PATH_BLOCKS (HEADS * QT_PATH * 8)            // 1152
#define HIST_QT 1000        // 16000/16
#define ATTN_BLOCKS (PATH_BLOCKS + HEADS * HIST_QT)  // 9152
#define PPSTRIDE (16 * 66)  // per partial-block floats: 16 q x (64 out + m + l)

static __device__ __forceinline__ u16 f2bf(float f) {
  unsigned u = __float_as_uint(f);
  u += 0x7FFFu + ((u >> 16) & 1u);
  return (u16)(u >> 16);
}
static __device__ __forceinline__ float bf2f(u16 h) {
  return __uint_as_float(((unsigned)h) << 16);
}
static __device__ __forceinline__ uint2 pack4(float4 v) {
  uint2 o;
  o.x = (unsigned)f2bf(v.x) | ((unsigned)f2bf(v.y) << 16);
  o.y = (unsigned)f2bf(v.z) | ((unsigned)f2bf(v.w) << 16);
  return o;
}

// ---- K1: QKV GEMM (bf16 MFMA), staging converts f32->bf16 in-register ------
// qkv[n,e] = sum_d x[n,d] * w[e,d];  e<512: Q (scaled 0.125), <1024: K, else: V
__global__ __launch_bounds__(256) void k_gemm_qkv(const float* __restrict__ x,
                                                  const float* __restrict__ w,
                                                  u16* __restrict__ Qb,
                                                  u16* __restrict__ Kb,
                                                  u16* __restrict__ Vb) {
  __shared__ u16 As[128 * 32];
  __shared__ u16 Bs[128 * 32];
  const int bm = blockIdx.x, bn = blockIdx.y;
  const int t = threadIdx.x;
  const int lane = t & 63, wv = t >> 6;
  const int wr = wv >> 1, wc = wv & 1;        // 2x2 waves over 128x128
  const int lr = lane & 15, kq = lane >> 4;
  f32x4 acc[4][4] = {};
  for (int ks = 0; ks < 512; ks += 32) {
    for (int c = t; c < 1024; c += 256) {     // 1024 chunks of 4 elems per matrix
      int row = c >> 3, c4 = (c & 7) << 2;
      int gr = bm * 128 + row;
      float4 va = {0.f, 0.f, 0.f, 0.f};
      if (gr < NTOK)
        va = *reinterpret_cast<const float4*>(&x[(size_t)gr * 512 + ks + c4]);
      *reinterpret_cast<uint2*>(&As[row * 32 + c4]) = pack4(va);
      float4 vb = *reinterpret_cast<const float4*>(&w[(size_t)(bn * 128 + row) * 512 + ks + c4]);
      *reinterpret_cast<uint2*>(&Bs[row * 32 + c4]) = pack4(vb);
    }
    __syncthreads();
    short8 af[4], bfr[4];
#pragma unroll
    for (int i = 0; i < 4; i++) {
      af[i]  = *reinterpret_cast<const short8*>(&As[(wr * 64 + i * 16 + lr) * 32 + kq * 8]);
      bfr[i] = *reinterpret_cast<const short8*>(&Bs[(wc * 64 + i * 16 + lr) * 32 + kq * 8]);
    }
#pragma unroll
    for (int i = 0; i < 4; i++)
#pragma unroll
      for (int j = 0; j < 4; j++)
        acc[i][j] = __builtin_amdgcn_mfma_f32_16x16x32_bf16(af[i], bfr[j], acc[i][j], 0, 0, 0);
    __syncthreads();
  }
  // epilogue: C layout row=(lane>>4)*4+r, col=lane&15
#pragma unroll
  for (int i = 0; i < 4; i++) {
#pragma unroll
    for (int j = 0; j < 4; j++) {
#pragma unroll
      for (int r = 0; r < 4; r++) {
        int row = wr * 64 + i * 16 + kq * 4 + r;
        int col = wc * 64 + j * 16 + lr;
        int n = bm * 128 + row;
        if (n < NTOK) {
          int e = bn * 128 + col;
          int which = e >> 9, h = (e >> 6) & 7, d = e & 63;
          float v = acc[i][j][r];
          size_t off = ((size_t)h * NPAD + n) * 64 + d;
          if (which == 0)      Qb[off] = f2bf(v * 0.125f);
          else if (which == 1) Kb[off] = f2bf(v);
          else                 Vb[off] = f2bf(v);
        }
      }
    }
  }
}

// ---- K2: unified attention (flash / flash-decoding partials) ---------------
// path blocks (b < 1152): h, 16-query tile, key chunk -> write partial (m,l,out)
// hist blocks: h, 16-query tile over hist queries, keys [0,281) -> write d_out
__global__ __launch_bounds__(256) void k_attn(const u16* __restrict__ Qb,
                                              const u16* __restrict__ Kb,
                                              const u16* __restrict__ Vb,
                                              float* __restrict__ dout,
                                              float* __restrict__ pp) {
  __shared__ float Qs[16][64];        // 4 KB
  __shared__ u16   Kt[256 * 66];      // 33 KB, row pad 66 -> conflict-free
  __shared__ float escr[16 * 256];    // 16 KB  (scores -> exp values)
  __shared__ float m_run[16], l_run[16], resc[16];

  const int b = blockIdx.x;
  const int t = threadIdx.x;
  int h, q0, k0, k1, qlim;
  bool path;
  if (b < PATH_BLOCKS) {
    path = true;
    int kc = b & 7;
    int qt = (b >> 3) % QT_PATH;
    h = b / (8 * QT_PATH);
    q0 = qt * 16;
    k0 = kc * CHUNK;
    k1 = min(k0 + CHUNK, NTOK);
    qlim = NPATH;
  } else {
    path = false;
    int bb = b - PATH_BLOCKS;
    h = bb / HIST_QT;
    int qt = bb % HIST_QT;
    q0 = NPATH + qt * 16;
    k0 = 0; k1 = NPATH;
    qlim = NTOK;
  }
  for (int i = t; i < 16 * 64; i += 256) {
    int qi = i >> 6, d = i & 63;
    int q = q0 + qi;
    Qs[qi][d] = (q < qlim) ? bf2f(Qb[((size_t)h * NPAD + q) * 64 + d]) : 0.f;
  }
  if (t < 16) { m_run[t] = -1e30f; l_run[t] = 0.f; }
  float acc0 = 0.f, acc1 = 0.f, acc2 = 0.f, acc3 = 0.f;
  const int d = t & 63, qg = t >> 6;   // wave qg handles queries qg*4 .. qg*4+3

  for (int j0 = k0; j0 < k1; j0 += 256) {
    const int jn = min(256, k1 - j0);
    __syncthreads();
    // stage K tile (bf16, 2 elems per uint)
    for (int i = t; i < jn * 32; i += 256) {
      int j = i >> 5, dp = (i & 31) << 1;
      *reinterpret_cast<unsigned*>(&Kt[j * 66 + dp]) =
          *reinterpret_cast<const unsigned*>(&Kb[((size_t)h * NPAD + j0 + j) * 64 + dp]);
    }
    __syncthreads();
    // scores: thread t = key row; dd outer, 16 query accumulators
    {
      float s[16];
#pragma unroll
      for (int qi = 0; qi < 16; qi++) s[qi] = 0.f;
      if (t < jn) {
        for (int dd = 0; dd < 64; dd++) {
          float kv = bf2f(Kt[t * 66 + dd]);
#pragma unroll
          for (int qi = 0; qi < 16; qi++) s[qi] += Qs[qi][dd] * kv;
        }
      }
#pragma unroll
      for (int qi = 0; qi < 16; qi++) escr[qi * 256 + t] = (t < jn) ? s[qi] : -1e30f;
    }
    __syncthreads();
    // per-row max (16 rows x 16 lanes)
    {
      int r = t >> 4, seg = t & 15;
      float mx = -1e30f;
      for (int u = 0; u < 16; u++) mx = fmaxf(mx, escr[r * 256 + seg + u * 16]);
      for (int m = 8; m; m >>= 1) mx = fmaxf(mx, __shfl_xor(mx, m, 64));
      if (seg == 0) {
        float mold = m_run[r];
        float mnew = fmaxf(mold, mx);
        m_run[r] = mnew;
        resc[r] = __expf(mold - mnew);
      }
    }
    __syncthreads();
    // exp + row sum + online l update
    {
      int r = t >> 4, seg = t & 15;
      float mnew = m_run[r];
      float ssum = 0.f;
      for (int u = 0; u < 16; u++) {
        int j = seg + u * 16;
        float e = __expf(escr[r * 256 + j] - mnew);
        escr[r * 256 + j] = e;
        ssum += e;
      }
      for (int m = 8; m; m >>= 1) ssum += __shfl_xor(ssum, m, 64);
      if (seg == 0) l_run[r] = l_run[r] * resc[r] + ssum;
    }
    __syncthreads();
    // PV: thread (d, wave qg); V bf16 straight from L2 (coalesced 128B/row)
    {
      float r0 = resc[qg * 4 + 0], r1 = resc[qg * 4 + 1];
      float r2 = resc[qg * 4 + 2], r3 = resc[qg * 4 + 3];
      acc0 *= r0; acc1 *= r1; acc2 *= r2; acc3 *= r3;
      const u16* vb = Vb + ((size_t)h * NPAD + j0) * 64 + d;
      const float* e0 = escr + (qg * 4 + 0) * 256;
      const float* e1 = escr + (qg * 4 + 1) * 256;
      const float* e2 = escr + (qg * 4 + 2) * 256;
      const float* e3 = escr + (qg * 4 + 3) * 256;
      int jv = jn & ~3;
      for (int j = 0; j < jv; j += 4) {
        float4 p0 = *reinterpret_cast<const float4*>(&e0[j]);
        float4 p1 = *reinterpret_cast<const float4*>(&e1[j]);
        float4 p2 = *reinterpret_cast<const float4*>(&e2[j]);
        float4 p3 = *reinterpret_cast<const float4*>(&e3[j]);
        float v0 = bf2f(vb[(size_t)(j + 0) * 64]);
        float v1 = bf2f(vb[(size_t)(j + 1) * 64]);
        float v2 = bf2f(vb[(size_t)(j + 2) * 64]);
        float v3 = bf2f(vb[(size_t)(j + 3) * 64]);
        acc0 += p0.x * v0 + p0.y * v1 + p0.z * v2 + p0.w * v3;
        acc1 += p1.x * v0 + p1.y * v1 + p1.z * v2 + p1.w * v3;
        acc2 += p2.x * v0 + p2.y * v1 + p2.z * v2 + p2.w * v3;
        acc3 += p3.x * v0 + p3.y * v1 + p3.z * v2 + p3.w * v3;
      }
      for (int j = jv; j < jn; j++) {
        float v = bf2f(vb[(size_t)j * 64]);
        acc0 += e0[j] * v; acc1 += e1[j] * v; acc2 += e2[j] * v; acc3 += e3[j] * v;
      }
    }
    __syncthreads();
  }

  if (path) {
    int kc = b & 7, qt = (b >> 3) % QT_PATH;
    float* base = pp + (size_t)((h * QT_PATH + qt) * 8 + kc) * PPSTRIDE;
#pragma unroll
    for (int p = 0; p < 4; p++) {
      int qi = qg * 4 + p;
      float a = (p == 0) ? acc0 : (p == 1) ? acc1 : (p == 2) ? acc2 : acc3;
      base[qi * 66 + d] = a;
    }
    if (t < 16) { base[t * 66 + 64] = m_run[t]; base[t * 66 + 65] = l_run[t]; }
  } else {
#pragma unroll
    for (int p = 0; p < 4; p++) {
      int qi = qg * 4 + p;
      float a = (p == 0) ? acc0 : (p == 1) ? acc1 : (p == 2) ? acc2 : acc3;
      int q = q0 + qi;
      dout[(size_t)q * 512 + h * 64 + d] = a / l_run[qi];
    }
  }
}

// ---- K3: combine path partials over 8 key chunks ---------------------------
__global__ void k_combine(const float* __restrict__ pp, float* __restrict__ dout) {
  const int b = blockIdx.x;       // 8*281
  const int h = b / NPATH, q = b % NPATH;
  const int d = threadIdx.x;      // 64
  const int qt = q >> 4, qi = q & 15;
  const float* base0 = pp + (size_t)(h * QT_PATH + qt) * 8 * PPSTRIDE + qi * 66;
  float m = -1e30f;
  for (int c = 0; c < 8; c++) m = fmaxf(m, base0[(size_t)c * PPSTRIDE + 64]);
  float l = 0.f, o = 0.f;
  for (int c = 0; c < 8; c++) {
    const float* base = base0 + (size_t)c * PPSTRIDE;
    float sc = __expf(base[64] - m);
    l += sc * base[65];
    o += sc * base[d];
  }
  dout[(size_t)q * 512 + h * 64 + d] = o / l;
}

// ---- K4: depthwise conv (kernel 33) over V, += into d_out ------------------
__global__ __launch_bounds__(256) void k_conv(const u16* __restrict__ Vb,
                                              const float* __restrict__ wres,
                                              float* __restrict__ dout) {
  __shared__ float Vs[96][64];
  __shared__ float wr[33];
  const int b = blockIdx.x;          // 8 * 255
  const int h = b / 255, n0 = (b % 255) * 64;
  const int t = threadIdx.x;
  if (t < 33) wr[t] = wres[h * 33 + t];
  for (int i = t; i < 96 * 64; i += 256) {
    int rr = i >> 6, dd = i & 63;
    int n = n0 - 16 + rr;
    Vs[rr][dd] = (n >= 0 && n < NTOK) ? bf2f(Vb[((size_t)h * NPAD + n) * 64 + dd]) : 0.f;
  }
  __syncthreads();
  const int d = t & 63, ns = t >> 6;
  for (int i = 0; i < 16; i++) {
    int nn = ns * 16 + i;
    int n = n0 + nn;
    if (n < NTOK) {
      float s = 0.f;
#pragma unroll
      for (int u = 0; u < 33; u++) s += Vs[nn + u][d] * wr[u];
      dout[(size_t)n * 512 + h * 64 + d] += s;
    }
  }
}

extern "C" void kernel_launch(void* const* d_in, const int* in_sizes, int n_in,
                              void* d_out, int out_size, void* d_ws, size_t ws_size,
                              hipStream_t stream) {
  const float* x    = (const float*)d_in[0];
  const float* wqkv = (const float*)d_in[1];
  const float* wres = (const float*)d_in[2];
  float* out = (float*)d_out;
  char* ws = (char*)d_ws;
  // workspace layout (bytes), all 16B-aligned; total 55,197,696 (~55.2 MB)
  const size_t NEED = 55197696;
  if (ws_size < NEED) return;   // diagnostic: fail fast (absmax 0.32) instead of faulting
  u16*   Qb = (u16*)(ws + 0);             // 8*16384*64*2 = 16,777,216
  u16*   Kb = (u16*)(ws + 16777216);      // same
  u16*   Vb = (u16*)(ws + 33554432);      // same
  float* pp = (float*)(ws + 50331648);    // 1152*1056*4  =  4,866,048

  hipLaunchKernelGGL(k_gemm_qkv, dim3(128, 12), dim3(256), 0, stream, x, wqkv, Qb, Kb, Vb);
  hipLaunchKernelGGL(k_attn, dim3(ATTN_BLOCKS), dim3(256), 0, stream, Qb, Kb, Vb, out, pp);
  hipLaunchKernelGGL(k_combine, dim3(HEADS * NPATH), dim3(64), 0, stream, pp, out);
  hipLaunchKernelGGL(k_conv, dim3(HEADS * 255), dim3(256), 0, stream, Vb, wres, out);
}

// Round 12
// 234.772 us; speedup vs baseline: 4.2843x; 4.2843x over previous
//
#include <hip/hip_runtime.h>

typedef short short8 __attribute__((ext_vector_type(8)));
typedef float f32x4 __attribute__((ext_vector_type(4)));
typedef unsigned short u16;

#define NTOK 16281
#define NPAD 16384
#define NPATH 281
#define HEADS 8
#define CHUNK 2036          // key-split for path queries (8 chunks)
#define KVB 128             // KV tile per inner iteration
#define PATH_QT 5           // ceil(281/64)
#define PATH_BLOCKS2 (HEADS * PATH_QT * 8)             // 320
#define HIST_QT2 250        // 16000/64
#define ATTN_BLOCKS2 (PATH_BLOCKS2 + HEADS * HIST_QT2) // 2320

static __device__ __forceinline__ u16 f2bf(float f) {
  unsigned u = __float_as_uint(f);
  u += 0x7FFFu + ((u >> 16) & 1u);
  return (u16)(u >> 16);
}
static __device__ __forceinline__ float bf2f(u16 h) {
  return __uint_as_float(((unsigned)h) << 16);
}
static __device__ __forceinline__ uint2 pack4(float4 v) {
  uint2 o;
  o.x = (unsigned)f2bf(v.x) | ((unsigned)f2bf(v.y) << 16);
  o.y = (unsigned)f2bf(v.z) | ((unsigned)f2bf(v.w) << 16);
  return o;
}

// ---- K1: QKV GEMM (bf16 MFMA) — unchanged from round-11 pass ---------------
__global__ __launch_bounds__(256) void k_gemm_qkv(const float* __restrict__ x,
                                                  const float* __restrict__ w,
                                                  u16* __restrict__ Qb,
                                                  u16* __restrict__ Kb,
                                                  u16* __restrict__ Vb) {
  __shared__ u16 As[128 * 32];
  __shared__ u16 Bs[128 * 32];
  const int bm = blockIdx.x, bn = blockIdx.y;
  const int t = threadIdx.x;
  const int lane = t & 63, wv = t >> 6;
  const int wr = wv >> 1, wc = wv & 1;
  const int lr = lane & 15, kq = lane >> 4;
  f32x4 acc[4][4] = {};
  for (int ks = 0; ks < 512; ks += 32) {
    for (int c = t; c < 1024; c += 256) {
      int row = c >> 3, c4 = (c & 7) << 2;
      int gr = bm * 128 + row;
      float4 va = {0.f, 0.f, 0.f, 0.f};
      if (gr < NTOK)
        va = *reinterpret_cast<const float4*>(&x[(size_t)gr * 512 + ks + c4]);
      *reinterpret_cast<uint2*>(&As[row * 32 + c4]) = pack4(va);
      float4 vb = *reinterpret_cast<const float4*>(&w[(size_t)(bn * 128 + row) * 512 + ks + c4]);
      *reinterpret_cast<uint2*>(&Bs[row * 32 + c4]) = pack4(vb);
    }
    __syncthreads();
    short8 af[4], bfr[4];
#pragma unroll
    for (int i = 0; i < 4; i++) {
      af[i]  = *reinterpret_cast<const short8*>(&As[(wr * 64 + i * 16 + lr) * 32 + kq * 8]);
      bfr[i] = *reinterpret_cast<const short8*>(&Bs[(wc * 64 + i * 16 + lr) * 32 + kq * 8]);
    }
#pragma unroll
    for (int i = 0; i < 4; i++)
#pragma unroll
      for (int j = 0; j < 4; j++)
        acc[i][j] = __builtin_amdgcn_mfma_f32_16x16x32_bf16(af[i], bfr[j], acc[i][j], 0, 0, 0);
    __syncthreads();
  }
#pragma unroll
  for (int i = 0; i < 4; i++) {
#pragma unroll
    for (int j = 0; j < 4; j++) {
#pragma unroll
      for (int r = 0; r < 4; r++) {
        int row = wr * 64 + i * 16 + kq * 4 + r;
        int col = wc * 64 + j * 16 + lr;
        int n = bm * 128 + row;
        if (n < NTOK) {
          int e = bn * 128 + col;
          int which = e >> 9, h = (e >> 6) & 7, d = e & 63;
          float v = acc[i][j][r];
          size_t off = ((size_t)h * NPAD + n) * 64 + d;
          if (which == 0)      Qb[off] = f2bf(v * 0.125f);
          else if (which == 1) Kb[off] = f2bf(v);
          else                 Vb[off] = f2bf(v);
        }
      }
    }
  }
}

// ---- K2: MFMA flash attention ----------------------------------------------
// block = 4 waves x 16 queries = 64 queries. path blocks write partials to pp;
// hist blocks write normalized output. K/V^T staged swizzled in LDS; P per-wave.
__global__ __launch_bounds__(256) void k_attn_mfma(const u16* __restrict__ Qb,
                                                   const u16* __restrict__ Kb,
                                                   const u16* __restrict__ Vb,
                                                   float* __restrict__ dout,
                                                   float* __restrict__ pp) {
  __shared__ u16 Kt[KVB * 64];      // 16 KB [key][d], swizzled
  __shared__ u16 Vt[64 * KVB];      // 16 KB [d][key], swizzled
  __shared__ u16 Pt[4][16 * KVB];   // 16 KB per-wave P, swizzled

  const int b = blockIdx.x, t = threadIdx.x;
  const int lane = t & 63, wq = t >> 6;
  const int c = lane & 15, g = lane >> 4;
  int h, q0, k0, k1, qlim;
  bool path;
  if (b < PATH_BLOCKS2) {
    path = true;
    int qt = (b >> 3) % PATH_QT;
    h = b / (8 * PATH_QT);
    q0 = qt * 64;
    k0 = (b & 7) * CHUNK;
    k1 = min(k0 + CHUNK, NTOK);
    qlim = NPATH;
  } else {
    path = false;
    int bb = b - PATH_BLOCKS2;
    h = bb / HIST_QT2;
    q0 = NPATH + (bb % HIST_QT2) * 64;
    k0 = 0; k1 = NPATH;
    qlim = NTOK;
  }
  // Q A-fragments in registers (row = lane&15, k = (lane>>4)*8, two 32-d halves)
  const int q = q0 + wq * 16 + c;
  short8 qf0 = {}, qf1 = {};
  if (q < qlim) {
    qf0 = *reinterpret_cast<const short8*>(&Qb[((size_t)h * NPAD + q) * 64 + g * 8]);
    qf1 = *reinterpret_cast<const short8*>(&Qb[((size_t)h * NPAD + q) * 64 + 32 + g * 8]);
  }
  float m_run[4], l_run[4];
#pragma unroll
  for (int r = 0; r < 4; r++) { m_run[r] = -1e30f; l_run[r] = 0.f; }
  f32x4 o[4] = {};

  for (int j0 = k0; j0 < k1; j0 += KVB) {
    const int jn = min(KVB, k1 - j0);
    __syncthreads();
    // stage K [key][d] swizzled: u16 idx = key*64 + ((dchunk ^ (key&7))<<3)
#pragma unroll
    for (int it = 0; it < 4; it++) {
      int i = t + it * 256;
      int row = i >> 3, cc = i & 7;
      uint4 vv = {0u, 0u, 0u, 0u};
      if (row < jn)
        vv = *reinterpret_cast<const uint4*>(&Kb[((size_t)h * NPAD + j0 + row) * 64 + cc * 8]);
      *reinterpret_cast<uint4*>(&Kt[row * 64 + ((cc ^ (row & 7)) << 3)]) = vv;
    }
    // stage V^T [d][key] swizzled: u16 idx = d*KVB + (key ^ ((d&7)<<3))
#pragma unroll
    for (int it = 0; it < 4; it++) {
      int i = t + it * 256;
      int key = i >> 3, dc = i & 7;
      uint4 vv = {0u, 0u, 0u, 0u};
      if (key < jn)
        vv = *reinterpret_cast<const uint4*>(&Vb[((size_t)h * NPAD + j0 + key) * 64 + dc * 8]);
      const u16* pv = reinterpret_cast<const u16*>(&vv);
#pragma unroll
      for (int u = 0; u < 8; u++) {
        int d = dc * 8 + u;
        Vt[d * KVB + (key ^ ((d & 7) << 3))] = pv[u];
      }
    }
    __syncthreads();
    // QK^T: s[kt] = Q(16x64) . K^T tile (16 keys), D: row=q=(g*4+r), col=key=c
    f32x4 s[8];
#pragma unroll
    for (int kt = 0; kt < 8; kt++) {
      int key = kt * 16 + c;
      int swz = (key & 7) << 3;
      short8 bk0 = *reinterpret_cast<const short8*>(&Kt[key * 64 + ((g * 8) ^ swz)]);
      short8 bk1 = *reinterpret_cast<const short8*>(&Kt[key * 64 + ((32 + g * 8) ^ swz)]);
      f32x4 z = {0.f, 0.f, 0.f, 0.f};
      z = __builtin_amdgcn_mfma_f32_16x16x32_bf16(qf0, bk0, z, 0, 0, 0);
      s[kt] = __builtin_amdgcn_mfma_f32_16x16x32_bf16(qf1, bk1, z, 0, 0, 0);
    }
    if (jn < KVB) {
#pragma unroll
      for (int kt = 0; kt < 8; kt++)
        if (kt * 16 + c >= jn) {
          s[kt][0] = -1e30f; s[kt][1] = -1e30f; s[kt][2] = -1e30f; s[kt][3] = -1e30f;
        }
    }
    // online softmax (rows lane-local: q = g*4+r; reduce over 16 key-lanes)
    float fac[4];
#pragma unroll
    for (int r = 0; r < 4; r++) {
      float m2 = s[0][r];
#pragma unroll
      for (int kt = 1; kt < 8; kt++) m2 = fmaxf(m2, s[kt][r]);
#pragma unroll
      for (int msk = 1; msk < 16; msk <<= 1) m2 = fmaxf(m2, __shfl_xor(m2, msk, 64));
      float mnew = fmaxf(m_run[r], m2);
      fac[r] = __expf(m_run[r] - mnew);
      m_run[r] = mnew;
    }
#pragma unroll
    for (int r = 0; r < 4; r++) {
      float ps = 0.f;
#pragma unroll
      for (int kt = 0; kt < 8; kt++) {
        float e = __expf(s[kt][r] - m_run[r]);
        s[kt][r] = e;
        ps += e;
      }
#pragma unroll
      for (int msk = 1; msk < 16; msk <<= 1) ps += __shfl_xor(ps, msk, 64);
      l_run[r] = l_run[r] * fac[r] + ps;
    }
#pragma unroll
    for (int dt = 0; dt < 4; dt++) {
#pragma unroll
      for (int r = 0; r < 4; r++) o[dt][r] *= fac[r];
    }
    // write P (bf16) to per-wave swizzled LDS: idx = qrow*KVB + (key ^ ((qrow&7)<<3))
#pragma unroll
    for (int r = 0; r < 4; r++) {
      int qrow = g * 4 + r;
      int swz = (qrow & 7) << 3;
#pragma unroll
      for (int kt = 0; kt < 8; kt++)
        Pt[wq][qrow * KVB + ((kt * 16 + c) ^ swz)] = f2bf(s[kt][r]);
    }
    // PV: O(16q x 64d) += P(16q x 128k) . V(128k x 64d)
#pragma unroll
    for (int ks = 0; ks < 4; ks++) {
      short8 pa = *reinterpret_cast<const short8*>(
          &Pt[wq][c * KVB + ((ks * 32 + g * 8) ^ ((c & 7) << 3))]);
#pragma unroll
      for (int dt = 0; dt < 4; dt++) {
        int d = dt * 16 + c;
        short8 bv = *reinterpret_cast<const short8*>(
            &Vt[d * KVB + ((ks * 32 + g * 8) ^ ((d & 7) << 3))]);
        o[dt] = __builtin_amdgcn_mfma_f32_16x16x32_bf16(pa, bv, o[dt], 0, 0, 0);
      }
    }
  }

  if (path) {
    int kc = b & 7;
#pragma unroll
    for (int r = 0; r < 4; r++) {
      int qp = q0 + wq * 16 + g * 4 + r;
      if (qp < NPATH) {
        float* base = pp + ((size_t)(h * 8 + kc) * NPATH + qp) * 66;
#pragma unroll
        for (int dt = 0; dt < 4; dt++) base[dt * 16 + c] = o[dt][r];
        if (c == 0) { base[64] = m_run[r]; base[65] = l_run[r]; }
      }
    }
  } else {
#pragma unroll
    for (int r = 0; r < 4; r++) {
      int qn = q0 + wq * 16 + g * 4 + r;
      float inv = 1.f / l_run[r];
#pragma unroll
      for (int dt = 0; dt < 4; dt++)
        dout[(size_t)qn * 512 + h * 64 + dt * 16 + c] = o[dt][r] * inv;
    }
  }
}

// ---- K3: combine path partials over 8 key chunks ---------------------------
__global__ void k_combine(const float* __restrict__ pp, float* __restrict__ dout) {
  const int b = blockIdx.x;       // 8*281
  const int h = b / NPATH, q = b % NPATH;
  const int d = threadIdx.x;      // 64
  const float* base0 = pp + ((size_t)(h * 8) * NPATH + q) * 66;
  const size_t cs = (size_t)NPATH * 66;
  float m = -1e30f;
  for (int c = 0; c < 8; c++) m = fmaxf(m, base0[c * cs + 64]);
  float l = 0.f, o = 0.f;
  for (int c = 0; c < 8; c++) {
    const float* base = base0 + c * cs;
    float sc = __expf(base[64] - m);
    l += sc * base[65];
    o += sc * base[d];
  }
  dout[(size_t)q * 512 + h * 64 + d] = o / l;
}

// ---- K4: depthwise conv (kernel 33) over V, += into d_out ------------------
__global__ __launch_bounds__(256) void k_conv(const u16* __restrict__ Vb,
                                              const float* __restrict__ wres,
                                              float* __restrict__ dout) {
  __shared__ float Vs[96][64];
  __shared__ float wr[33];
  const int b = blockIdx.x;          // 8 * 255
  const int h = b / 255, n0 = (b % 255) * 64;
  const int t = threadIdx.x;
  if (t < 33) wr[t] = wres[h * 33 + t];
  for (int i = t; i < 96 * 64; i += 256) {
    int rr = i >> 6, dd = i & 63;
    int n = n0 - 16 + rr;
    Vs[rr][dd] = (n >= 0 && n < NTOK) ? bf2f(Vb[((size_t)h * NPAD + n) * 64 + dd]) : 0.f;
  }
  __syncthreads();
  const int d = t & 63, ns = t >> 6;
  for (int i = 0; i < 16; i++) {
    int nn = ns * 16 + i;
    int n = n0 + nn;
    if (n < NTOK) {
      float s = 0.f;
#pragma unroll
      for (int u = 0; u < 33; u++) s += Vs[nn + u][d] * wr[u];
      dout[(size_t)n * 512 + h * 64 + d] += s;
    }
  }
}

extern "C" void kernel_launch(void* const* d_in, const int* in_sizes, int n_in,
                              void* d_out, int out_size, void* d_ws, size_t ws_size,
                              hipStream_t stream) {
  const float* x    = (const float*)d_in[0];
  const float* wqkv = (const float*)d_in[1];
  const float* wres = (const float*)d_in[2];
  float* out = (float*)d_out;
  char* ws = (char*)d_ws;
  // workspace: Qb/Kb/Vb 16.78MB each + pp 4.75MB = 55,079,424 B
  const size_t NEED = 55079424;
  if (ws_size < NEED) return;
  u16*   Qb = (u16*)(ws + 0);
  u16*   Kb = (u16*)(ws + 16777216);
  u16*   Vb = (u16*)(ws + 33554432);
  float* pp = (float*)(ws + 50331648);

  hipLaunchKernelGGL(k_gemm_qkv, dim3(128, 12), dim3(256), 0, stream, x, wqkv, Qb, Kb, Vb);
  hipLaunchKernelGGL(k_attn_mfma, dim3(ATTN_BLOCKS2), dim3(256), 0, stream, Qb, Kb, Vb, out, pp);
  hipLaunchKernelGGL(k_combine, dim3(HEADS * NPATH), dim3(64), 0, stream, pp, out);
  hipLaunchKernelGGL(k_conv, dim3(HEADS * 255), dim3(256), 0, stream, Vb, wres, out);
}